// Round 1
// baseline (1044.670 us; speedup 1.0000x reference)
//
#include <hip/hip_runtime.h>
#include <math.h>

#define NPT   8192
#define FIN   256
#define DD    64
#define KSEL  48
#define QT    16
#define CT    128

#define LEAKY(x) (((x) >= 0.f) ? (x) : 0.01f*(x))

// ---------------- K0: transpose Wl (256x192 -> 192x256) ----------------
__global__ void k0_transpose(const float* __restrict__ Wl, float* __restrict__ WlT) {
  int j = blockIdx.x;            // 0..191
  int o = threadIdx.x;           // 0..255
  WlT[j*256 + o] = Wl[o*192 + j];
}

// ---------------- K1: per-node precompute (fp64) ----------------
// f = feature@Wb.T + bb ; sq = ||f||^2 ; u = f@Wt.T ; c = f@Wp.T + bp + u + bt
__global__ __launch_bounds__(256) void k1_precompute(
    const float* __restrict__ feature, const float* __restrict__ Wb, const float* __restrict__ bb,
    const float* __restrict__ Wt1, const float* __restrict__ bt1,
    const float* __restrict__ Wp1, const float* __restrict__ bp1,
    const float* __restrict__ Wt2, const float* __restrict__ bt2,
    const float* __restrict__ Wp2, const float* __restrict__ bp2,
    double* __restrict__ f64d, double* __restrict__ sq64,
    float* __restrict__ f32v, float* __restrict__ sqf,
    float* __restrict__ u1, float* __restrict__ c1,
    float* __restrict__ u2, float* __restrict__ c2)
{
  const int w = threadIdx.x >> 6, l = threadIdx.x & 63;
  const int i = blockIdx.x*4 + w;
  const float* frow = feature + i*FIN;
  const float* wrow = Wb + l*FIN;
  double facc = (double)bb[l];
  #pragma unroll 8
  for (int j = 0; j < FIN; ++j) facc += (double)frow[j] * (double)wrow[j];
  f64d[i*DD + l] = facc;
  f32v[i*DD + l] = (float)facc;
  double s = facc*facc;
  #pragma unroll
  for (int off = 32; off; off >>= 1) s += __shfl_xor(s, off);
  if (l == 0) { sq64[i] = s; sqf[i] = (float)s; }
  double au1 = 0.0, ap1 = 0.0, au2 = 0.0, ap2 = 0.0;
  for (int e = 0; e < DD; ++e) {
    double fe = __shfl(facc, e);
    au1 += fe * (double)Wt1[l*DD + e];
    ap1 += fe * (double)Wp1[l*DD + e];
    au2 += fe * (double)Wt2[l*DD + e];
    ap2 += fe * (double)Wp2[l*DD + e];
  }
  u1[i*DD+l] = (float)au1;
  c1[i*DD+l] = (float)(ap1 + (double)bp1[l] + au1 + (double)bt1[l]);
  u2[i*DD+l] = (float)au2;
  c2[i*DD+l] = (float)(ap2 + (double)bp2[l] + au2 + (double)bt2[l]);
}

// ---------------- K2: streaming KNN top-48 (fp32) ----------------
// Block: 256 thr, QT=16 queries; sweep candidates in chunks of CT=128.
// Per-query sorted (dist,idx) list of 48 kept in LDS, sorted-insert via ballot.
__global__ __launch_bounds__(256) void k2_knn(
    const float* __restrict__ f32v, const float* __restrict__ sqf,
    int* __restrict__ idx48)
{
  __shared__ __align__(16) float fq_s[QT*68];
  __shared__ __align__(16) float fc_s[CT*68];
  __shared__ float dist_s[QT*132];
  __shared__ float knn_d[QT*KSEL];
  __shared__ int   knn_i[QT*KSEL];
  __shared__ float sqq_s[QT];
  __shared__ float sqc_s[CT];

  const int t = threadIdx.x;
  const int qbase = blockIdx.x * QT;

  for (int r = t; r < QT*KSEL; r += 256) { knn_d[r] = __builtin_inff(); knn_i[r] = 0; }
  {
    int q = t >> 4, d4 = t & 15;
    float4 g = *(const float4*)&f32v[(qbase+q)*DD + 4*d4];
    *(float4*)&fq_s[q*68 + 4*d4] = g;
  }
  if (t < QT) sqq_s[t] = sqf[qbase + t];

  const int tr = t >> 5;   // 0..7 -> q0 = 2*tr
  const int tc = t & 31;   // 0..31 -> c0 = 4*tc
  const int q0 = 2*tr, c0 = 4*tc;
  const int w = t >> 6, l = t & 63;

  for (int cb = 0; cb < NPT/CT; ++cb) {
    const int jbase = cb * CT;
    __syncthreads();
    // stage candidate chunk
    #pragma unroll
    for (int r = 0; r < 8; ++r) {
      int flat = t + 256*r;
      int c = flat >> 4, d4 = flat & 15;
      float4 g = *(const float4*)&f32v[(jbase + c)*DD + 4*d4];
      *(float4*)&fc_s[c*68 + 4*d4] = g;
    }
    if (t < CT) sqc_s[t] = sqf[jbase + t];
    __syncthreads();
    // distances: 2q x 4c register tile
    float acc[2][4] = {{0.f,0.f,0.f,0.f},{0.f,0.f,0.f,0.f}};
    #pragma unroll 4
    for (int d4 = 0; d4 < 16; ++d4) {
      float4 a0 = *(const float4*)&fq_s[q0*68 + 4*d4];
      float4 a1 = *(const float4*)&fq_s[(q0+1)*68 + 4*d4];
      #pragma unroll
      for (int ic = 0; ic < 4; ++ic) {
        float4 b = *(const float4*)&fc_s[(c0+ic)*68 + 4*d4];
        acc[0][ic] += a0.x*b.x + a0.y*b.y + a0.z*b.z + a0.w*b.w;
        acc[1][ic] += a1.x*b.x + a1.y*b.y + a1.z*b.z + a1.w*b.w;
      }
    }
    #pragma unroll
    for (int iq = 0; iq < 2; ++iq)
      #pragma unroll
      for (int ic = 0; ic < 4; ++ic)
        dist_s[(q0+iq)*132 + c0 + ic] =
            sqq_s[q0+iq] + sqc_s[c0+ic] - 2.0f*acc[iq][ic];
    __syncthreads();
    // selection: wave w owns queries 4w..4w+3
    for (int qq = 0; qq < 4; ++qq) {
      int q = 4*w + qq;
      for (int half = 0; half < 2; ++half) {
        int cl = 64*half + l;
        float dval = dist_s[q*132 + cl];
        float thr = knn_d[q*KSEL + 47];
        unsigned long long mask = __ballot(dval < thr);
        if (!mask) continue;
        float ld = (l < KSEL) ? knn_d[q*KSEL + l] : __builtin_inff();
        int   li = (l < KSEL) ? knn_i[q*KSEL + l] : 0;
        bool wrote = false;
        do {
          int b = __ffsll((unsigned long long)mask) - 1;
          mask &= (mask - 1);
          float dc = __shfl(dval, b);
          if (dc < thr) {                      // wave-uniform
            int jc = jbase + 64*half + b;
            int pos = __popcll(__ballot(l < KSEL && ld <= dc));
            float sd = __shfl_up(ld, 1);
            int   si = __shfl_up(li, 1);
            if (l >= pos) {
              if (l == pos) { ld = dc; li = jc; } else { ld = sd; li = si; }
            }
            thr = __shfl(ld, 47);
            wrote = true;
          }
        } while (mask);
        if (wrote && l < KSEL) { knn_d[q*KSEL + l] = ld; knn_i[q*KSEL + l] = li; }
      }
    }
  }
  __syncthreads();
  for (int qq = 0; qq < 4; ++qq) {
    int q = 4*w + qq;
    if (l < KSEL) idx48[(qbase+q)*KSEL + l] = knn_i[q*KSEL + l];
  }
}

// ---------------- K2b: fp64 exact re-rank of the 48 -> sorted idx40 ----------------
__global__ __launch_bounds__(256) void k2b_rerank(
    const double* __restrict__ f64d, const double* __restrict__ sq64,
    const int* __restrict__ idx48, int* __restrict__ idx40)
{
  __shared__ double sbd[4*KSEL];
  __shared__ int    sbi[4*KSEL];
  const int w = threadIdx.x >> 6, l = threadIdx.x & 63;
  const int node = blockIdx.x*4 + w;
  double dm = 0.0; int cand = 0;
  if (l < KSEL) {
    cand = idx48[node*KSEL + l];
    const double* fi = f64d + node*DD;
    const double* fc = f64d + (long)cand*DD;
    double acc = 0.0;
    #pragma unroll 8
    for (int d = 0; d < DD; ++d) acc += fi[d]*fc[d];
    dm = sq64[node] + sq64[cand] - 2.0*acc;
    sbd[w*KSEL + l] = dm; sbi[w*KSEL + l] = cand;
  }
  __syncthreads();
  if (l < KSEL) {
    int rank = 0;
    for (int j = 0; j < KSEL; ++j) {
      double dj = sbd[w*KSEL + j];
      int    ij = sbi[w*KSEL + j];
      rank += (dj < dm) || (dj == dm && ij < cand);
    }
    if (rank < 40) idx40[node*40 + rank] = cand;
  }
}

// ---------------- K3: two edge-convs + neighbor max-pool ----------------
__global__ __launch_bounds__(256) void k3_edgeconv(
    const float* __restrict__ f32v,
    const float* __restrict__ u1, const float* __restrict__ c1,
    const float* __restrict__ u2, const float* __restrict__ c2,
    const float* __restrict__ Wm1a, const float* __restrict__ bm1a,
    const float* __restrict__ Wm1b, const float* __restrict__ bm1b,
    const float* __restrict__ Wm2a, const float* __restrict__ bm2a,
    const float* __restrict__ Wm2b, const float* __restrict__ bm2b,
    const int* __restrict__ idx40, float* __restrict__ hout)
{
  __shared__ __align__(16) float Wa_s[64*68];
  __shared__ __align__(16) float Wb_s[64*68];
  __shared__ __align__(16) float z_s[20*64];
  __shared__ __align__(16) float a_s[20*64];
  __shared__ float red_s[4*64];
  __shared__ int idx_sh[40];
  const int t = threadIdx.x;
  const int i = blockIdx.x;
  const int w = t >> 6, l = t & 63;
  if (t < 40) idx_sh[t] = idx40[i*40 + t];
  __syncthreads();

  for (int conv = 0; conv < 2; ++conv) {
    const float* Wa_g  = conv ? Wm2a : Wm1a;
    const float* Wbm_g = conv ? Wm2b : Wm1b;
    const float* ba_g  = conv ? bm2a : bm1a;
    const float* bbv_g = conv ? bm2b : bm1b;
    const float* u_g   = conv ? u2 : u1;
    const float* c_g   = conv ? c2 : c1;
    // stage weights (padded rows of 68 for b128 reads)
    #pragma unroll
    for (int r = 0; r < 4; ++r) {
      int flat = t + 256*r;
      int hh = flat >> 4, e4 = flat & 15;
      *(float4*)&Wa_s[hh*68 + 4*e4] = *(const float4*)&Wa_g[hh*64 + 4*e4];
      *(float4*)&Wb_s[hh*68 + 4*e4] = *(const float4*)&Wbm_g[hh*64 + 4*e4];
    }
    // stage z = leaky(c_i - u_nb)
    #pragma unroll
    for (int r = 0; r < 5; ++r) {
      int flat = t + 256*r;
      int k = flat >> 6, d = flat & 63;
      int nb = idx_sh[conv ? 2*k : k];
      float z = c_g[i*DD + d] - u_g[nb*DD + d];
      z_s[k*64 + d] = LEAKY(z);
    }
    __syncthreads();
    // layer A: a[k][h] = leaky(z[k]·Wa[h] + ba[h]); wave w owns k = w,w+4,...,w+16
    float acc[5];
    #pragma unroll
    for (int kk = 0; kk < 5; ++kk) acc[kk] = ba_g[l];
    for (int e4 = 0; e4 < 16; ++e4) {
      float4 wv = *(const float4*)&Wa_s[l*68 + 4*e4];
      #pragma unroll
      for (int kk = 0; kk < 5; ++kk) {
        float4 zv = *(const float4*)&z_s[(w + 4*kk)*64 + 4*e4];
        acc[kk] += zv.x*wv.x + zv.y*wv.y + zv.z*wv.z + zv.w*wv.w;
      }
    }
    #pragma unroll
    for (int kk = 0; kk < 5; ++kk) { float v = acc[kk]; a_s[(w + 4*kk)*64 + l] = LEAKY(v); }
    __syncthreads();
    // layer B + per-wave max over its 5 k's
    float acc2[5];
    #pragma unroll
    for (int kk = 0; kk < 5; ++kk) acc2[kk] = bbv_g[l];
    for (int e4 = 0; e4 < 16; ++e4) {
      float4 wv = *(const float4*)&Wb_s[l*68 + 4*e4];
      #pragma unroll
      for (int kk = 0; kk < 5; ++kk) {
        float4 av = *(const float4*)&a_s[(w + 4*kk)*64 + 4*e4];
        acc2[kk] += av.x*wv.x + av.y*wv.y + av.z*wv.z + av.w*wv.w;
      }
    }
    float m = acc2[0];
    #pragma unroll
    for (int kk = 1; kk < 5; ++kk) m = fmaxf(m, acc2[kk]);
    red_s[w*64 + l] = m;
    __syncthreads();
    if (t < 64) {
      float v = fmaxf(fmaxf(red_s[t], red_s[64+t]), fmaxf(red_s[128+t], red_s[192+t]));
      hout[i*192 + conv*64 + t] = v;
    }
    __syncthreads();
  }
  // h_max over first 9 neighbors of f
  if (t < 64) {
    float m = -__builtin_inff();
    #pragma unroll
    for (int k = 0; k < 9; ++k) m = fmaxf(m, f32v[idx_sh[k]*DD + t]);
    hout[i*192 + 128 + t] = m;
  }
}

// ---------------- K4: final linear + bias + residual ----------------
__global__ __launch_bounds__(256) void k4_final(
    const float* __restrict__ hbuf, const float* __restrict__ WlT,
    const float* __restrict__ bl, const float* __restrict__ feature,
    float* __restrict__ out)
{
  __shared__ __align__(16) float h_sh[16*192];
  const int t = threadIdx.x;
  const int nbase = blockIdx.x * 16;
  #pragma unroll
  for (int r = 0; r < 3; ++r) {
    int flat = t + 256*r;
    int n = flat / 48, j4 = flat % 48;
    *(float4*)&h_sh[n*192 + 4*j4] = *(const float4*)&hbuf[(nbase+n)*192 + 4*j4];
  }
  __syncthreads();
  float acc[16];
  #pragma unroll
  for (int n = 0; n < 16; ++n) acc[n] = 0.f;
  for (int j4 = 0; j4 < 48; ++j4) {
    float w0 = WlT[(4*j4+0)*256 + t];
    float w1 = WlT[(4*j4+1)*256 + t];
    float w2 = WlT[(4*j4+2)*256 + t];
    float w3 = WlT[(4*j4+3)*256 + t];
    #pragma unroll
    for (int n = 0; n < 16; ++n) {
      float4 hv = *(const float4*)&h_sh[n*192 + 4*j4];
      acc[n] += hv.x*w0 + hv.y*w1 + hv.z*w2 + hv.w*w3;
    }
  }
  float blv = bl[t];
  #pragma unroll
  for (int n = 0; n < 16; ++n)
    out[(nbase+n)*256 + t] = acc[n] + blv + feature[(nbase+n)*256 + t];
}

extern "C" void kernel_launch(void* const* d_in, const int* in_sizes, int n_in,
                              void* d_out, int out_size, void* d_ws, size_t ws_size,
                              hipStream_t stream) {
  const float* feature = (const float*)d_in[0];
  const float* Wb   = (const float*)d_in[1];
  const float* bb   = (const float*)d_in[2];
  const float* Wt1  = (const float*)d_in[3];
  const float* bt1  = (const float*)d_in[4];
  const float* Wp1  = (const float*)d_in[5];
  const float* bp1  = (const float*)d_in[6];
  const float* Wm1a = (const float*)d_in[7];
  const float* bm1a = (const float*)d_in[8];
  const float* Wm1b = (const float*)d_in[9];
  const float* bm1b = (const float*)d_in[10];
  const float* Wt2  = (const float*)d_in[11];
  const float* bt2  = (const float*)d_in[12];
  const float* Wp2  = (const float*)d_in[13];
  const float* bp2  = (const float*)d_in[14];
  const float* Wm2a = (const float*)d_in[15];
  const float* bm2a = (const float*)d_in[16];
  const float* Wm2b = (const float*)d_in[17];
  const float* bm2b = (const float*)d_in[18];
  const float* Wl   = (const float*)d_in[19];
  const float* bl   = (const float*)d_in[20];
  float* out = (float*)d_out;

  char* ws = (char*)d_ws;
  double* f64d = (double*)(ws + 0);
  double* sq64 = (double*)(ws + 4194304);
  float*  f32v = (float*)(ws + 4259840);
  float*  sqf  = (float*)(ws + 6356992);
  float*  u1   = (float*)(ws + 6389760);
  float*  c1   = (float*)(ws + 8486912);
  float*  u2   = (float*)(ws + 10584064);
  float*  c2   = (float*)(ws + 12681216);
  int*    idx48= (int*)(ws + 14778368);
  int*    idx40= (int*)(ws + 16351232);
  float*  hbuf = (float*)(ws + 17661952);
  float*  WlT  = (float*)(ws + 23953408);

  hipLaunchKernelGGL(k0_transpose, dim3(192), dim3(256), 0, stream, Wl, WlT);
  hipLaunchKernelGGL(k1_precompute, dim3(2048), dim3(256), 0, stream,
                     feature, Wb, bb, Wt1, bt1, Wp1, bp1, Wt2, bt2, Wp2, bp2,
                     f64d, sq64, f32v, sqf, u1, c1, u2, c2);
  hipLaunchKernelGGL(k2_knn, dim3(512), dim3(256), 0, stream, f32v, sqf, idx48);
  hipLaunchKernelGGL(k2b_rerank, dim3(2048), dim3(256), 0, stream, f64d, sq64, idx48, idx40);
  hipLaunchKernelGGL(k3_edgeconv, dim3(8192), dim3(256), 0, stream,
                     f32v, u1, c1, u2, c2, Wm1a, bm1a, Wm1b, bm1b,
                     Wm2a, bm2a, Wm2b, bm2b, idx40, hbuf);
  hipLaunchKernelGGL(k4_final, dim3(512), dim3(256), 0, stream, hbuf, WlT, bl, feature, out);
}